// Round 1
// baseline (620.577 us; speedup 1.0000x reference)
//
#include <hip/hip_runtime.h>
#include <hip/hip_bf16.h>
#include <stdint.h>

#define MEM_DIM 128
#define MSG_DIM 256
#define NGATE   384   // 3 * MEM_DIM

typedef __attribute__((ext_vector_type(8))) __bf16 bf16x8;
typedef __attribute__((ext_vector_type(4))) float  f32x4;

union B8u { uint32_t u[4]; bf16x8 v; };

__device__ __forceinline__ uint32_t cvt_pk(float lo, float hi) {
    uint32_t r;
    asm("v_cvt_pk_bf16_f32 %0, %1, %2" : "=v"(r) : "v"(lo), "v"(hi));
    return r;
}

// load 8 consecutive f32 and convert to a bf16x8 fragment (RNE)
__device__ __forceinline__ bf16x8 load_cvt8(const float* __restrict__ p) {
    f32x4 a = *(const f32x4*)p;
    f32x4 b = *(const f32x4*)(p + 4);
    B8u r;
    r.u[0] = cvt_pk(a.x, a.y);
    r.u[1] = cvt_pk(a.z, a.w);
    r.u[2] = cvt_pk(b.x, b.y);
    r.u[3] = cvt_pk(b.z, b.w);
    return r.v;
}

__device__ __forceinline__ bf16x8 zero8() {
    B8u r; r.u[0] = r.u[1] = r.u[2] = r.u[3] = 0; return r.v;
}

__device__ __forceinline__ float sigm(float x) {
    return __builtin_amdgcn_rcpf(1.0f + __expf(-x));
}
__device__ __forceinline__ float tanh_fast(float x) {
    return 1.0f - 2.0f * __builtin_amdgcn_rcpf(1.0f + __expf(2.0f * x));
}

// ---------------------------------------------------------------- copy kernel
__global__ void copy_kernel(const float4* __restrict__ mem,
                            const float4* __restrict__ lu,
                            float4* __restrict__ out,
                            int n_mem4, int n_tot4) {
    int stride = gridDim.x * blockDim.x;
    for (int i = blockIdx.x * blockDim.x + threadIdx.x; i < n_tot4; i += stride) {
        out[i] = (i < n_mem4) ? mem[i] : lu[i - n_mem4];
    }
}

// ------------------------------------------------------- weight bf16 convert
__global__ void wconv_kernel(const float* __restrict__ wih,
                             const float* __restrict__ whh,
                             __hip_bfloat16* __restrict__ out) {
    int i = blockIdx.x * 256 + threadIdx.x;
    const int NIH = NGATE * MSG_DIM;       // 98304
    const int NHH = NGATE * MEM_DIM;       // 49152
    if (i < NIH)            out[i] = __float2bfloat16(wih[i]);
    else if (i < NIH + NHH) out[i] = __float2bfloat16(whh[i - NIH]);
}

// ------------------------------------------------------------------ GRU kernel
// block = 512 threads = 8 waves; each wave owns 32 update-rows (2 sub-tiles of 16)
// BM = 256 rows / block. A-fragments (x, h) live in registers for the whole
// kernel; B (weights) streamed from global (identical across waves -> L1 reuse).
template<bool PRE>
__global__ __launch_bounds__(512, 2)
void gru_kernel(const float* __restrict__ memory,
                const int*   __restrict__ ids,
                const float* __restrict__ msgs,
                const float* __restrict__ ts,
                const float* __restrict__ Wih,    // [384][256] f32
                const float* __restrict__ Whh,    // [384][128] f32
                const float* __restrict__ bih,
                const float* __restrict__ bhh,
                const __hip_bfloat16* __restrict__ WihB,  // [384][256] bf16
                const __hip_bfloat16* __restrict__ WhhB,  // [384][128] bf16
                float* __restrict__ out_mem,
                float* __restrict__ out_lu,
                int U) {
    const int tid  = threadIdx.x;
    const int wave = tid >> 6;
    const int lane = tid & 63;
    const int g    = lane >> 4;   // 0..3
    const int q    = lane & 15;   // 0..15
    const int rb   = blockIdx.x * 256 + wave * 32;

    // timestamp scatter (one entry per thread of the first 4 waves)
    {
        int u = blockIdx.x * 256 + tid;
        if (tid < 256 && u < U) out_lu[ids[u]] = ts[u];
    }

    // ---- A fragments: x rows (K=256 -> 8 k-steps), h rows (K=128 -> 4 k-steps)
    bf16x8 xf[2][8];
    bf16x8 hf[2][4];
    #pragma unroll
    for (int sub = 0; sub < 2; ++sub) {
        int r = rb + sub * 16 + q;          // A-operand row = lane&15
        bool ok = (r < U);
        int id = ok ? ids[r] : 0;
        const float* xp = msgs   + (size_t)r  * MSG_DIM;
        const float* hp = memory + (size_t)id * MEM_DIM;
        #pragma unroll
        for (int s = 0; s < 8; ++s)
            xf[sub][s] = ok ? load_cvt8(xp + 32 * s + 8 * g) : zero8();
        #pragma unroll
        for (int s = 0; s < 4; ++s)
            hf[sub][s] = ok ? load_cvt8(hp + 32 * s + 8 * g) : zero8();
    }

    // ids for the C/D rows this lane will write: row = sub*16 + 4*g + j
    int oid[2][4];
    #pragma unroll
    for (int sub = 0; sub < 2; ++sub)
        #pragma unroll
        for (int j = 0; j < 4; ++j) {
            int r = rb + sub * 16 + 4 * g + j;
            oid[sub][j] = (r < U) ? ids[r] : 0;
        }

    const f32x4 z4 = {0.f, 0.f, 0.f, 0.f};

    // ---- loop over output-column chunks of 16 (8 chunks cover MEM_DIM=128)
    for (int ch = 0; ch < 8; ++ch) {
        const int c = ch * 16 + q;          // output col, also B-operand col
        f32x4 acc[2][6];
        #pragma unroll
        for (int sub = 0; sub < 2; ++sub)
            #pragma unroll
            for (int k = 0; k < 6; ++k) acc[sub][k] = z4;

        // gi = x @ W_ih^T   (3 gate rows per chunk)
        #pragma unroll
        for (int s = 0; s < 8; ++s) {
            #pragma unroll
            for (int gate = 0; gate < 3; ++gate) {
                size_t off = (size_t)(gate * MEM_DIM + c) * MSG_DIM + 32 * s + 8 * g;
                bf16x8 b = PRE ? *(const bf16x8*)(WihB + off)
                               : load_cvt8(Wih + off);
                acc[0][gate] = __builtin_amdgcn_mfma_f32_16x16x32_bf16(xf[0][s], b, acc[0][gate], 0, 0, 0);
                acc[1][gate] = __builtin_amdgcn_mfma_f32_16x16x32_bf16(xf[1][s], b, acc[1][gate], 0, 0, 0);
            }
        }
        // gh = h @ W_hh^T
        #pragma unroll
        for (int s = 0; s < 4; ++s) {
            #pragma unroll
            for (int gate = 0; gate < 3; ++gate) {
                size_t off = (size_t)(gate * MEM_DIM + c) * MEM_DIM + 32 * s + 8 * g;
                bf16x8 b = PRE ? *(const bf16x8*)(WhhB + off)
                               : load_cvt8(Whh + off);
                acc[0][3 + gate] = __builtin_amdgcn_mfma_f32_16x16x32_bf16(hf[0][s], b, acc[0][3 + gate], 0, 0, 0);
                acc[1][3 + gate] = __builtin_amdgcn_mfma_f32_16x16x32_bf16(hf[1][s], b, acc[1][3 + gate], 0, 0, 0);
            }
        }

        // biases (same for all rows, vary by col)
        float bir = bih[c],            bhr = bhh[c];
        float biz = bih[MEM_DIM + c],  bhz = bhh[MEM_DIM + c];
        float bin = bih[2*MEM_DIM + c], bhn = bhh[2*MEM_DIM + c];

        // gate math + scatter store
        #pragma unroll
        for (int sub = 0; sub < 2; ++sub) {
            #pragma unroll
            for (int j = 0; j < 4; ++j) {
                int r = rb + sub * 16 + 4 * g + j;   // C/D row = 4*(lane>>4)+j
                if (r < U) {
                    float gr = acc[sub][0][j] + bir + acc[sub][3][j] + bhr;
                    float gz = acc[sub][1][j] + biz + acc[sub][4][j] + bhz;
                    float rg = sigm(gr);
                    float zg = sigm(gz);
                    float hn = acc[sub][5][j] + bhn;
                    float ng = tanh_fast(acc[sub][2][j] + bin + rg * hn);
                    size_t off = (size_t)oid[sub][j] * MEM_DIM + c;
                    float hv = memory[off];
                    out_mem[off] = (1.0f - zg) * ng + zg * hv;
                }
            }
        }
    }
}

// ------------------------------------------------------------------- launcher
extern "C" void kernel_launch(void* const* d_in, const int* in_sizes, int n_in,
                              void* d_out, int out_size, void* d_ws, size_t ws_size,
                              hipStream_t stream) {
    const float* memory      = (const float*)d_in[0];
    const float* last_update = (const float*)d_in[1];
    const int*   ids         = (const int*)  d_in[2];
    const float* msgs        = (const float*)d_in[3];
    const float* ts          = (const float*)d_in[4];
    const float* Wih         = (const float*)d_in[5];
    const float* Whh         = (const float*)d_in[6];
    const float* bih         = (const float*)d_in[7];
    const float* bhh         = (const float*)d_in[8];

    const int NN = in_sizes[1];          // 1,000,000 nodes
    const int U  = in_sizes[2];          // 200,000 updates

    float* out_mem = (float*)d_out;
    float* out_lu  = out_mem + (size_t)NN * MEM_DIM;

    // 1) full pass-through copy of memory + last_update into d_out
    int n_mem4 = NN * MEM_DIM / 4;
    int n_tot4 = n_mem4 + NN / 4;
    copy_kernel<<<4096, 256, 0, stream>>>((const float4*)memory,
                                          (const float4*)last_update,
                                          (float4*)d_out, n_mem4, n_tot4);

    // 2) GRU update on the gathered rows, scatter into d_out
    const size_t WBYTES = (size_t)(NGATE * MSG_DIM + NGATE * MEM_DIM) * sizeof(__hip_bfloat16);
    int nb = (U + 255) / 256;
    if (ws_size >= WBYTES) {
        __hip_bfloat16* wb = (__hip_bfloat16*)d_ws;
        wconv_kernel<<<(NGATE * MSG_DIM + NGATE * MEM_DIM) / 256, 256, 0, stream>>>(Wih, Whh, wb);
        gru_kernel<true><<<nb, 512, 0, stream>>>(memory, ids, msgs, ts,
                                                 Wih, Whh, bih, bhh,
                                                 wb, wb + NGATE * MSG_DIM,
                                                 out_mem, out_lu, U);
    } else {
        gru_kernel<false><<<nb, 512, 0, stream>>>(memory, ids, msgs, ts,
                                                  Wih, Whh, bih, bhh,
                                                  nullptr, nullptr,
                                                  out_mem, out_lu, U);
    }
}